// Round 11
// baseline (274.583 us; speedup 1.0000x reference)
//
#include <hip/hip_runtime.h>
#include <hip/hip_bf16.h>

#define NN 50000
#define NE 1600000
#define D 128
#define NB 784      // buckets of 64 nodes (784*64 = 50176 >= NN)
#define CAP 2560    // bucket capacity; Binomial mean 2048, sd~45 -> +11.3 sd
#define EPT 4       // edges per thread in k_bin (1024-thread blocks)
#define NROW 50048  // NN padded to 64-row GEMM tiles (782 blocks * 64)
#define LDWU 68     // LDS W row pitch in uints (136 ushorts = 128 data + 8 pad)
#define BINTH 400384  // k_bin total threads (391 blocks * 1024)

typedef __attribute__((ext_vector_type(8))) short bf16x8;
typedef __attribute__((ext_vector_type(4))) float f32x4;

__device__ __forceinline__ unsigned short f2bf(float f) {
  unsigned u = __float_as_uint(f);
  u += 0x7FFFu + ((u >> 16) & 1u);
  return (unsigned short)(u >> 16);
}
__device__ __forceinline__ float bf2f(unsigned short h) {
  return __uint_as_float((unsigned)h << 16);
}

// ---------------------------------------------------------------------------
// K1: fused prep + coarse bin.
// Prologue: xh = bf16(x); cth = bf16 combined bond table; w1t/w2t = bf16
// transposed weights. Edge phase: bin by dst>>6.
// record = src | cb<<16 | (dst&63)<<23.
// ---------------------------------------------------------------------------
__global__ __launch_bounds__(1024) void k_bin(const float* __restrict__ x,
                                              const float* __restrict__ bemb,
                                              const float* __restrict__ W1,
                                              const float* __restrict__ W2,
                                              const int* __restrict__ dst,
                                              const int* __restrict__ src,
                                              const int* __restrict__ ea,
                                              int* __restrict__ bucketCnt,
                                              unsigned* __restrict__ staging,
                                              ushort* __restrict__ xh,
                                              ushort* __restrict__ cth,
                                              ushort* __restrict__ w1t,
                                              ushort* __restrict__ w2t) {
  __shared__ int lcnt[NB], gbase[NB], lcur[NB];   // 9.4 KB
  const int tid = threadIdx.x;
  const int gid = blockIdx.x * 1024 + tid;
  for (int i = tid; i < NB; i += 1024) { lcnt[i] = 0; lcur[i] = 0; }

  // ---- prologue: prep work (before the same barrier as the LDS zero) ------
  if (gid < 125 * D) {
    const int c = gid >> 7;
    const int k = gid & 127;
    const float v = bemb[(c / 25) * D + k] + bemb[(5 + (c % 25) / 5) * D + k] +
                    bemb[(10 + c % 5) * D + k];
    cth[gid] = f2bf(v);
  }
  if (gid < 2 * 16384) {  // transpose+cast both weight matrices
    const int m = gid >> 14;
    const int idx = gid & 16383;
    const int c = idx >> 7;
    const int k = idx & 127;
    const float w = m ? W2[k * 128 + c] : W1[k * 128 + c];
    (m ? w2t : w1t)[idx] = f2bf(w);
  }
  for (int i = gid; i < NN * D / 4; i += BINTH) {   // <=4 float4 per thread
    const float4 v = *(const float4*)(x + i * 4);
    ushort4 h;
    h.x = f2bf(v.x); h.y = f2bf(v.y); h.z = f2bf(v.z); h.w = f2bf(v.w);
    *(ushort4*)(xh + i * 4) = h;
  }

  // ---- edge phase (proven round-4 structure) ------------------------------
  const int e0 = gid * EPT;
  const bool act = (e0 < NE);

  int d[EPT];
  unsigned rec[EPT];
  if (act) {
    const int4 dv = *(const int4*)(dst + e0);
    const int4 sv = *(const int4*)(src + e0);
    const int4* ap = (const int4*)(ea + 3 * e0);
    int a[12];
#pragma unroll
    for (int q = 0; q < 3; ++q) {
      const int4 v = ap[q];
      a[4 * q + 0] = v.x; a[4 * q + 1] = v.y; a[4 * q + 2] = v.z; a[4 * q + 3] = v.w;
    }
    d[0] = dv.x; d[1] = dv.y; d[2] = dv.z; d[3] = dv.w;
    rec[0] = sv.x; rec[1] = sv.y; rec[2] = sv.z; rec[3] = sv.w;
#pragma unroll
    for (int q = 0; q < EPT; ++q) {
      const unsigned cb = (unsigned)((a[3 * q] * 5 + a[3 * q + 1]) * 5 + a[3 * q + 2]);
      rec[q] |= (cb << 16) | ((unsigned)(d[q] & 63) << 23);
      atomicAdd(&lcnt[d[q] >> 6], 1);
    }
  }
  __syncthreads();
  for (int i = tid; i < NB; i += 1024)
    gbase[i] = atomicAdd(&bucketCnt[i], lcnt[i]);
  __syncthreads();
  if (act) {
#pragma unroll
    for (int q = 0; q < EPT; ++q) {
      const int b = d[q] >> 6;
      const int r = atomicAdd(&lcur[b], 1) + gbase[b];
      if (r < CAP) staging[(size_t)b * CAP + r] = rec[q];
    }
  }
}

// ---------------------------------------------------------------------------
// K2: FUSED fine-CSR + aggregation. One 1024-thread block per 64-node bucket.
// Phase 1 (= old k_fine): staging -> srec (LDS), 64-bin hist + scan, scatter
// into ssort (LDS) — no global writeback of sorted records.
// Phase 2 (= frozen k_agg body): 32 lanes/node, 32 warps x 2 passes; the
// chunk read packed2[j0+lane] (global) becomes ssort[j0+lane] (LDS, stride-1
// conflict-free); shfl / depth-8 gather / consume / float4 store IDENTICAL
// to the proven 90us body. DO NOT re-add ILP (r3/r7 lost via occupancy).
// ---------------------------------------------------------------------------
__global__ __launch_bounds__(1024) void k_fagg(const int* __restrict__ bucketCnt,
                                               const unsigned* __restrict__ staging,
                                               const float* __restrict__ x,
                                               const ushort* __restrict__ xh,
                                               const ushort* __restrict__ cth,
                                               const float* __restrict__ epsp,
                                               float* __restrict__ hbuf) {
  __shared__ unsigned srec[CAP];    // 10 KB
  __shared__ unsigned ssort[CAP];   // 10 KB
  __shared__ int hist[64], off[64], cur[64];
  const int tid = threadIdx.x;
  const int b = blockIdx.x;
  const int base = b * CAP;
  const int cnt = min(bucketCnt[b], CAP);

  // ---- phase 1: build bucket-local CSR in LDS -----------------------------
  if (tid < 64) { hist[tid] = 0; cur[tid] = 0; }
  for (int i = tid; i < cnt; i += 1024) srec[i] = staging[base + i];
  __syncthreads();
  for (int i = tid; i < cnt; i += 1024) atomicAdd(&hist[srec[i] >> 23], 1);
  __syncthreads();
  int v = 0;
  if (tid < 64) { v = hist[tid]; off[tid] = v; }
  __syncthreads();
  for (int s = 1; s < 64; s <<= 1) {
    int u = 0;
    if (tid < 64 && tid >= s) u = off[tid - s];
    __syncthreads();
    if (tid < 64) off[tid] += u;
    __syncthreads();
  }
  if (tid < 64) off[tid] -= v;  // inclusive -> exclusive
  __syncthreads();
  for (int i = tid; i < cnt; i += 1024) {
    const unsigned u = srec[i];
    const int node = u >> 23;
    const int r = atomicAdd(&cur[node], 1);
    ssort[off[node] + r] = u & 0x7FFFFFu;
  }
  __syncthreads();

  // ---- phase 2: aggregation (frozen k_agg structure) ----------------------
  const int lane = tid & 31;
  const int w = tid >> 5;            // 32 warps; 2 passes cover 64 nodes
  const float eps1 = 1.0f + epsp[0];
  const int col = lane << 2;

#pragma unroll
  for (int pass = 0; pass < 2; ++pass) {
    const int localn = w + pass * 32;
    const int n = b * 64 + localn;
    const int jb = off[localn];
    const int je = jb + hist[localn];
    float4 acc = make_float4(0.f, 0.f, 0.f, 0.f);

    for (int j0 = jb; j0 < je; j0 += 32) {
      const int rem = min(32, je - j0);
      const int pk = (j0 + lane < je) ? (int)ssort[j0 + lane] : 0;
      int t = 0;
      for (; t + 8 <= rem; t += 8) {
        unsigned p[8];
#pragma unroll
        for (int i = 0; i < 8; ++i) p[i] = (unsigned)__shfl(pk, t + i, 32);
        ushort4 xs[8];
#pragma unroll
        for (int i = 0; i < 8; ++i)
          xs[i] = *(const ushort4*)(xh + (size_t)(p[i] & 0xFFFF) * D + col);
#pragma unroll
        for (int i = 0; i < 8; ++i) {
          const ushort4 eh = *(const ushort4*)(cth + ((p[i] >> 16) & 0x7F) * D + col);
          acc.x += fmaxf(bf2f(xs[i].x) + bf2f(eh.x), 0.f);
          acc.y += fmaxf(bf2f(xs[i].y) + bf2f(eh.y), 0.f);
          acc.z += fmaxf(bf2f(xs[i].z) + bf2f(eh.z), 0.f);
          acc.w += fmaxf(bf2f(xs[i].w) + bf2f(eh.w), 0.f);
        }
      }
      for (; t < rem; ++t) {
        const unsigned p = (unsigned)__shfl(pk, t, 32);
        const ushort4 xv = *(const ushort4*)(xh + (size_t)(p & 0xFFFF) * D + col);
        const ushort4 eh = *(const ushort4*)(cth + ((p >> 16) & 0x7F) * D + col);
        acc.x += fmaxf(bf2f(xv.x) + bf2f(eh.x), 0.f);
        acc.y += fmaxf(bf2f(xv.y) + bf2f(eh.y), 0.f);
        acc.z += fmaxf(bf2f(xv.z) + bf2f(eh.z), 0.f);
        acc.w += fmaxf(bf2f(xv.w) + bf2f(eh.w), 0.f);
      }
    }

    if (n < NN) {
      const float4 xv = *(const float4*)(x + (size_t)n * D + col);
      acc.x += eps1 * xv.x;
      acc.y += eps1 * xv.y;
      acc.z += eps1 * xv.z;
      acc.w += eps1 * xv.w;
      *(float4*)(hbuf + (size_t)n * D + col) = acc;
    }
  }
}

// ---------------------------------------------------------------------------
// K4: h1 = h @ W1 + b1 via MFMA bf16 (A split hi+lo) + fused BN sum/sumsq.
// h1 stored bf16; BN sums use the dequantized values (stats match stored h1).
// ---------------------------------------------------------------------------
__global__ __launch_bounds__(256, 4) void k_mfma1(const float* __restrict__ hbuf,
                                                  const ushort* __restrict__ w1t,
                                                  const float* __restrict__ b1,
                                                  ushort* __restrict__ h1,
                                                  float* __restrict__ gsum,
                                                  float* __restrict__ gsumsq) {
  __shared__ uint sW[128 * LDWU];          // 34816 B
  __shared__ float ssum[128], ssq[128];
  const int tid = threadIdx.x;
  {
    const uint* src = (const uint*)w1t;
    for (int i = tid; i < 8192; i += 256)
      sW[(i >> 6) * LDWU + (i & 63)] = src[i];
  }
  if (tid < 128) { ssum[tid] = 0.f; ssq[tid] = 0.f; }
  __syncthreads();

  const int l = tid & 63;
  const int la = l & 15;
  const int lb = l >> 4;                       // k-group 0..3
  const int rowbase = blockIdx.x * 64 + (tid >> 6) * 16;
  const int arow = rowbase + la;
  const float* ap = hbuf + (size_t)arow * 128 + lb * 8;

  f32x4 acc[8];
#pragma unroll
  for (int ct = 0; ct < 8; ++ct) acc[ct] = (f32x4){0.f, 0.f, 0.f, 0.f};

#pragma unroll
  for (int ks = 0; ks < 4; ++ks) {
    const float4 a0 = *(const float4*)(ap + ks * 32);
    const float4 a1 = *(const float4*)(ap + ks * 32 + 4);
    const float af[8] = {a0.x, a0.y, a0.z, a0.w, a1.x, a1.y, a1.z, a1.w};
    bf16x8 ahi, alo;
#pragma unroll
    for (int j = 0; j < 8; ++j) {
      const unsigned short hh = f2bf(af[j]);
      ahi[j] = (short)hh;
      alo[j] = (short)f2bf(af[j] - bf2f(hh));
    }
#pragma unroll
    for (int ct = 0; ct < 8; ++ct) {
      const int c = ct * 16 + la;
      const bf16x8 b = *(const bf16x8*)(sW + c * LDWU + ks * 16 + lb * 4);
      acc[ct] = __builtin_amdgcn_mfma_f32_16x16x32_bf16(ahi, b, acc[ct], 0, 0, 0);
      acc[ct] = __builtin_amdgcn_mfma_f32_16x16x32_bf16(alo, b, acc[ct], 0, 0, 0);
    }
  }

#pragma unroll
  for (int ct = 0; ct < 8; ++ct) {
    const int col = ct * 16 + la;
    const float bb = b1[col];
    float s = 0.f, q = 0.f;
#pragma unroll
    for (int r = 0; r < 4; ++r) {
      const int row = rowbase + lb * 4 + r;     // C/D: row=(lane>>4)*4+reg
      if (row < NN) {
        const float v = acc[ct][r] + bb;
        const unsigned short hq = f2bf(v);
        h1[(size_t)row * 128 + col] = hq;
        const float vq = bf2f(hq);
        s += vq;
        q += vq * vq;
      }
    }
    s += __shfl_xor(s, 16, 64); q += __shfl_xor(q, 16, 64);
    s += __shfl_xor(s, 32, 64); q += __shfl_xor(q, 32, 64);
    if (lb == 0) { atomicAdd(&ssum[col], s); atomicAdd(&ssq[col], q); }
  }
  __syncthreads();
  if (tid < 128) {
    atomicAdd(&gsum[tid], ssum[tid]);
    atomicAdd(&gsumsq[tid], ssq[tid]);
  }
}

// ---------------------------------------------------------------------------
// K5: out = relu(BN(h1)) @ W2 + b2 via MFMA bf16. A read as bf16; BN affine +
// relu in fp32; requantize to bf16 fragment. h1 pad rows (>= NN) unwritten —
// harmless (A-row only affects its own guarded D-row).
// ---------------------------------------------------------------------------
__global__ __launch_bounds__(256, 4) void k_mfma2(const ushort* __restrict__ h1,
                                                  const ushort* __restrict__ w2t,
                                                  const float* __restrict__ gsum,
                                                  const float* __restrict__ gsq,
                                                  const float* __restrict__ gamma,
                                                  const float* __restrict__ beta,
                                                  const float* __restrict__ b2,
                                                  float* __restrict__ out) {
  __shared__ uint sW[128 * LDWU];
  __shared__ float bnA[128], bnB[128];
  const int tid = threadIdx.x;
  {
    const uint* src = (const uint*)w2t;
    for (int i = tid; i < 8192; i += 256)
      sW[(i >> 6) * LDWU + (i & 63)] = src[i];
  }
  if (tid < 128) {
    const float invN = 1.0f / (float)NN;
    const float m = gsum[tid] * invN;
    const float A = gamma[tid] * rsqrtf(gsq[tid] * invN - m * m + 1e-5f);
    bnA[tid] = A;
    bnB[tid] = beta[tid] - m * A;
  }
  __syncthreads();

  const int l = tid & 63;
  const int la = l & 15;
  const int lb = l >> 4;
  const int rowbase = blockIdx.x * 64 + (tid >> 6) * 16;
  const int arow = rowbase + la;
  const ushort* ap = h1 + (size_t)arow * 128 + lb * 8;

  f32x4 acc[8];
#pragma unroll
  for (int ct = 0; ct < 8; ++ct) acc[ct] = (f32x4){0.f, 0.f, 0.f, 0.f};

#pragma unroll
  for (int ks = 0; ks < 4; ++ks) {
    const int k0 = ks * 32 + lb * 8;
    const bf16x8 araw = *(const bf16x8*)(ap + ks * 32);
    const float4 cA0 = *(const float4*)(bnA + k0);
    const float4 cA1 = *(const float4*)(bnA + k0 + 4);
    const float4 cB0 = *(const float4*)(bnB + k0);
    const float4 cB1 = *(const float4*)(bnB + k0 + 4);
    const float af[8] = {
        fmaxf(fmaf(bf2f((unsigned short)araw[0]), cA0.x, cB0.x), 0.f),
        fmaxf(fmaf(bf2f((unsigned short)araw[1]), cA0.y, cB0.y), 0.f),
        fmaxf(fmaf(bf2f((unsigned short)araw[2]), cA0.z, cB0.z), 0.f),
        fmaxf(fmaf(bf2f((unsigned short)araw[3]), cA0.w, cB0.w), 0.f),
        fmaxf(fmaf(bf2f((unsigned short)araw[4]), cA1.x, cB1.x), 0.f),
        fmaxf(fmaf(bf2f((unsigned short)araw[5]), cA1.y, cB1.y), 0.f),
        fmaxf(fmaf(bf2f((unsigned short)araw[6]), cA1.z, cB1.z), 0.f),
        fmaxf(fmaf(bf2f((unsigned short)araw[7]), cA1.w, cB1.w), 0.f)};
    bf16x8 afr;
#pragma unroll
    for (int j = 0; j < 8; ++j) afr[j] = (short)f2bf(af[j]);
#pragma unroll
    for (int ct = 0; ct < 8; ++ct) {
      const int c = ct * 16 + la;
      const bf16x8 b = *(const bf16x8*)(sW + c * LDWU + ks * 16 + lb * 4);
      acc[ct] = __builtin_amdgcn_mfma_f32_16x16x32_bf16(afr, b, acc[ct], 0, 0, 0);
    }
  }

#pragma unroll
  for (int ct = 0; ct < 8; ++ct) {
    const int col = ct * 16 + la;
    const float bb = b2[col];
#pragma unroll
    for (int r = 0; r < 4; ++r) {
      const int row = rowbase + lb * 4 + r;
      if (row < NN) out[(size_t)row * 128 + col] = acc[ct][r] + bb;
    }
  }
}

extern "C" void kernel_launch(void* const* d_in, const int* in_sizes, int n_in,
                              void* d_out, int out_size, void* d_ws, size_t ws_size,
                              hipStream_t stream) {
  const float* x    = (const float*)d_in[0];
  const int* ea     = (const int*)d_in[1];
  const int* src    = (const int*)d_in[2];
  const int* dst    = (const int*)d_in[3];
  const float* bemb = (const float*)d_in[4];
  const float* epsp = (const float*)d_in[5];
  const float* W1   = (const float*)d_in[6];
  const float* b1   = (const float*)d_in[7];
  const float* gam  = (const float*)d_in[8];
  const float* bet  = (const float*)d_in[9];
  const float* W2   = (const float*)d_in[10];
  const float* b2   = (const float*)d_in[11];
  float* out = (float*)d_out;

  float* ws         = (float*)d_ws;
  float* hbuf       = ws;                                   // NROW*D fp32 (48 pad rows)
  int* bucketCnt    = (int*)(ws + (size_t)NROW * D);        // NB
  float* gsum       = ws + (size_t)NROW * D + NB;           // 128
  float* gsumsq     = gsum + D;                             // 128
  ushort* cth       = (ushort*)(gsumsq + D);                // 125*128 bf16 (32 KB)
  ushort* w1t       = cth + 125 * D;                        // 128*128 bf16
  ushort* w2t       = w1t + 16384;                          // 128*128 bf16
  ushort* xh        = w2t + 16384;                          // NN*D bf16
  unsigned* staging = (unsigned*)(xh + (size_t)NN * D);     // NB*CAP (8.0 MB)
  ushort* h1h       = (ushort*)(staging + (size_t)NB * CAP); // NROW*D bf16 (12.8 MB)

  // single memset: contiguous = hbuf pad rows (6144 f) + bucketCnt (784 i) +
  // gsum/gsumsq (256 f)
  hipMemsetAsync(hbuf + (size_t)NN * D, 0,
                 (size_t)((NROW - NN) * D + NB + 2 * D) * sizeof(float), stream);

  k_bin<<<(NE / EPT + 1023) / 1024, 1024, 0, stream>>>(
      x, bemb, W1, W2, dst, src, ea, bucketCnt, staging, xh, cth, w1t, w2t);
  k_fagg<<<NB, 1024, 0, stream>>>(bucketCnt, staging, x, xh, cth, epsp, hbuf);
  k_mfma1<<<NROW / 64, 256, 0, stream>>>(hbuf, w1t, b1, h1h, gsum, gsumsq);
  k_mfma2<<<NROW / 64, 256, 0, stream>>>(h1h, w2t, gsum, gsumsq, gam, bet, b2, out);
}

// Round 12
// 268.063 us; speedup vs baseline: 1.0243x; 1.0243x over previous
//
#include <hip/hip_runtime.h>
#include <hip/hip_bf16.h>

#define NN 50000
#define NE 1600000
#define D 128
#define NB 784      // buckets of 64 nodes (784*64 = 50176 >= NN)
#define CAP 2560    // bucket capacity; Binomial mean 2048, sd~45 -> +11.3 sd
#define EPT 4       // edges per thread in k_bin (1024-thread blocks)
#define NROW 50048  // NN padded to 64-row GEMM tiles (782 blocks * 64)
#define LDWU 68     // LDS W row pitch in uints (136 ushorts = 128 data + 8 pad)
#define BINTH 400384  // k_bin total threads (391 blocks * 1024)

typedef __attribute__((ext_vector_type(8))) short bf16x8;
typedef __attribute__((ext_vector_type(4))) float f32x4;

__device__ __forceinline__ unsigned short f2bf(float f) {
  unsigned u = __float_as_uint(f);
  u += 0x7FFFu + ((u >> 16) & 1u);
  return (unsigned short)(u >> 16);
}
__device__ __forceinline__ float bf2f(unsigned short h) {
  return __uint_as_float((unsigned)h << 16);
}

// ---------------------------------------------------------------------------
// K1: fused prep + coarse bin.
// Prologue: xh = bf16(x); cth = bf16 combined bond table; w1t/w2t = bf16
// transposed weights. Edge phase: bin by dst>>6.
// record = src | cb<<16 | (dst&63)<<23.
// ---------------------------------------------------------------------------
__global__ __launch_bounds__(1024) void k_bin(const float* __restrict__ x,
                                              const float* __restrict__ bemb,
                                              const float* __restrict__ W1,
                                              const float* __restrict__ W2,
                                              const int* __restrict__ dst,
                                              const int* __restrict__ src,
                                              const int* __restrict__ ea,
                                              int* __restrict__ bucketCnt,
                                              unsigned* __restrict__ staging,
                                              ushort* __restrict__ xh,
                                              ushort* __restrict__ cth,
                                              ushort* __restrict__ w1t,
                                              ushort* __restrict__ w2t) {
  __shared__ int lcnt[NB], gbase[NB], lcur[NB];   // 9.4 KB
  const int tid = threadIdx.x;
  const int gid = blockIdx.x * 1024 + tid;
  for (int i = tid; i < NB; i += 1024) { lcnt[i] = 0; lcur[i] = 0; }

  // ---- prologue: prep work (before the same barrier as the LDS zero) ------
  if (gid < 125 * D) {
    const int c = gid >> 7;
    const int k = gid & 127;
    const float v = bemb[(c / 25) * D + k] + bemb[(5 + (c % 25) / 5) * D + k] +
                    bemb[(10 + c % 5) * D + k];
    cth[gid] = f2bf(v);
  }
  if (gid < 2 * 16384) {  // transpose+cast both weight matrices
    const int m = gid >> 14;
    const int idx = gid & 16383;
    const int c = idx >> 7;
    const int k = idx & 127;
    const float w = m ? W2[k * 128 + c] : W1[k * 128 + c];
    (m ? w2t : w1t)[idx] = f2bf(w);
  }
  for (int i = gid; i < NN * D / 4; i += BINTH) {   // <=4 float4 per thread
    const float4 v = *(const float4*)(x + i * 4);
    ushort4 h;
    h.x = f2bf(v.x); h.y = f2bf(v.y); h.z = f2bf(v.z); h.w = f2bf(v.w);
    *(ushort4*)(xh + i * 4) = h;
  }

  // ---- edge phase (proven round-4 structure) ------------------------------
  const int e0 = gid * EPT;
  const bool act = (e0 < NE);

  int d[EPT];
  unsigned rec[EPT];
  if (act) {
    const int4 dv = *(const int4*)(dst + e0);
    const int4 sv = *(const int4*)(src + e0);
    const int4* ap = (const int4*)(ea + 3 * e0);
    int a[12];
#pragma unroll
    for (int q = 0; q < 3; ++q) {
      const int4 v = ap[q];
      a[4 * q + 0] = v.x; a[4 * q + 1] = v.y; a[4 * q + 2] = v.z; a[4 * q + 3] = v.w;
    }
    d[0] = dv.x; d[1] = dv.y; d[2] = dv.z; d[3] = dv.w;
    rec[0] = sv.x; rec[1] = sv.y; rec[2] = sv.z; rec[3] = sv.w;
#pragma unroll
    for (int q = 0; q < EPT; ++q) {
      const unsigned cb = (unsigned)((a[3 * q] * 5 + a[3 * q + 1]) * 5 + a[3 * q + 2]);
      rec[q] |= (cb << 16) | ((unsigned)(d[q] & 63) << 23);
      atomicAdd(&lcnt[d[q] >> 6], 1);
    }
  }
  __syncthreads();
  for (int i = tid; i < NB; i += 1024)
    gbase[i] = atomicAdd(&bucketCnt[i], lcnt[i]);
  __syncthreads();
  if (act) {
#pragma unroll
    for (int q = 0; q < EPT; ++q) {
      const int b = d[q] >> 6;
      const int r = atomicAdd(&lcur[b], 1) + gbase[b];
      if (r < CAP) staging[(size_t)b * CAP + r] = rec[q];
    }
  }
}

// ---------------------------------------------------------------------------
// K2: fine CSR within each 64-node bucket. In-place writeback into staging.
// (Fusing this into the aggregation kernel was tried in r11: REGRESSED —
// LDS-scatter bank conflicts (436K) + 1024-thread tail imbalance cost more
// than the saved dispatch. Keep split.)
// ---------------------------------------------------------------------------
__global__ __launch_bounds__(1024) void k_fine(const int* __restrict__ bucketCnt,
                                               unsigned* __restrict__ staging,
                                               int* __restrict__ beg,
                                               int* __restrict__ end) {
  __shared__ unsigned srec[CAP];      // 10 KB
  __shared__ int hist[64], off[64], cur[64];
  const int tid = threadIdx.x;
  const int b = blockIdx.x;
  const int base = b * CAP;
  const int cnt = min(bucketCnt[b], CAP);

  if (tid < 64) { hist[tid] = 0; cur[tid] = 0; }
  for (int i = tid; i < cnt; i += 1024) srec[i] = staging[base + i];
  __syncthreads();
  for (int i = tid; i < cnt; i += 1024) atomicAdd(&hist[srec[i] >> 23], 1);
  __syncthreads();
  int v = 0;
  if (tid < 64) { v = hist[tid]; off[tid] = v; }
  __syncthreads();
  for (int s = 1; s < 64; s <<= 1) {
    int u = 0;
    if (tid < 64 && tid >= s) u = off[tid - s];
    __syncthreads();
    if (tid < 64) off[tid] += u;
    __syncthreads();
  }
  if (tid < 64) off[tid] -= v;
  __syncthreads();

  if (tid < 64) {
    const int n = b * 64 + tid;
    if (n < NN) {
      beg[n] = base + off[tid];
      end[n] = base + off[tid] + hist[tid];
    }
  }
  for (int i = tid; i < cnt; i += 1024) {
    const unsigned u = srec[i];
    const int node = u >> 23;
    const int r = atomicAdd(&cur[node], 1);
    staging[base + off[node] + r] = u & 0x7FFFFFu;
  }
}

// ---------------------------------------------------------------------------
// K3: per-node aggregation — FROZEN proven body (~91 us, VGPR 28, depth-8,
// 32 lanes/node, bf16 cth). Session ledger: ILP hurts (r3 depth-16, r7
// ping-pong — both lost occupancy), traffic cuts neutral (r9), LDS-CSR
// fusion hurts (r11). This is the TLP-saturated latency floor.
// ---------------------------------------------------------------------------
__global__ __launch_bounds__(256, 4) void k_agg(const float* __restrict__ x,
                                                const ushort* __restrict__ xh,
                                                const ushort* __restrict__ cth,
                                                const float* __restrict__ epsp,
                                                const int* __restrict__ beg,
                                                const int* __restrict__ end,
                                                const unsigned* __restrict__ packed2,
                                                float* __restrict__ hbuf) {
  const int lane = threadIdx.x & 31;
  const int n = blockIdx.x * 8 + (threadIdx.x >> 5);  // 6250*8 = NN exactly
  const int col = lane << 2;

  const int jb = beg[n];
  const int je = end[n];
  float4 acc = make_float4(0.f, 0.f, 0.f, 0.f);

  for (int j0 = jb; j0 < je; j0 += 32) {
    const int rem = min(32, je - j0);
    const int pk = (j0 + lane < je) ? (int)packed2[j0 + lane] : 0;
    int t = 0;
    for (; t + 8 <= rem; t += 8) {
      unsigned p[8];
#pragma unroll
      for (int i = 0; i < 8; ++i) p[i] = (unsigned)__shfl(pk, t + i, 32);
      ushort4 xs[8];
#pragma unroll
      for (int i = 0; i < 8; ++i)
        xs[i] = *(const ushort4*)(xh + (size_t)(p[i] & 0xFFFF) * D + col);
#pragma unroll
      for (int i = 0; i < 8; ++i) {
        const ushort4 eh = *(const ushort4*)(cth + ((p[i] >> 16) & 0x7F) * D + col);
        acc.x += fmaxf(bf2f(xs[i].x) + bf2f(eh.x), 0.f);
        acc.y += fmaxf(bf2f(xs[i].y) + bf2f(eh.y), 0.f);
        acc.z += fmaxf(bf2f(xs[i].z) + bf2f(eh.z), 0.f);
        acc.w += fmaxf(bf2f(xs[i].w) + bf2f(eh.w), 0.f);
      }
    }
    for (; t < rem; ++t) {
      const unsigned p = (unsigned)__shfl(pk, t, 32);
      const ushort4 xv = *(const ushort4*)(xh + (size_t)(p & 0xFFFF) * D + col);
      const ushort4 eh = *(const ushort4*)(cth + ((p >> 16) & 0x7F) * D + col);
      acc.x += fmaxf(bf2f(xv.x) + bf2f(eh.x), 0.f);
      acc.y += fmaxf(bf2f(xv.y) + bf2f(eh.y), 0.f);
      acc.z += fmaxf(bf2f(xv.z) + bf2f(eh.z), 0.f);
      acc.w += fmaxf(bf2f(xv.w) + bf2f(eh.w), 0.f);
    }
  }

  const float eps1 = 1.0f + epsp[0];
  const float4 xv = *(const float4*)(x + (size_t)n * D + col);
  acc.x += eps1 * xv.x;
  acc.y += eps1 * xv.y;
  acc.z += eps1 * xv.z;
  acc.w += eps1 * xv.w;
  *(float4*)(hbuf + (size_t)n * D + col) = acc;
}

// ---------------------------------------------------------------------------
// K4: h1 = h @ W1 + b1 via MFMA bf16 (A split hi+lo) + fused BN sum/sumsq.
// h1 stored bf16; BN sums use the dequantized values (stats match stored h1).
// ---------------------------------------------------------------------------
__global__ __launch_bounds__(256, 4) void k_mfma1(const float* __restrict__ hbuf,
                                                  const ushort* __restrict__ w1t,
                                                  const float* __restrict__ b1,
                                                  ushort* __restrict__ h1,
                                                  float* __restrict__ gsum,
                                                  float* __restrict__ gsumsq) {
  __shared__ uint sW[128 * LDWU];          // 34816 B
  __shared__ float ssum[128], ssq[128];
  const int tid = threadIdx.x;
  {
    const uint* src = (const uint*)w1t;
    for (int i = tid; i < 8192; i += 256)
      sW[(i >> 6) * LDWU + (i & 63)] = src[i];
  }
  if (tid < 128) { ssum[tid] = 0.f; ssq[tid] = 0.f; }
  __syncthreads();

  const int l = tid & 63;
  const int la = l & 15;
  const int lb = l >> 4;                       // k-group 0..3
  const int rowbase = blockIdx.x * 64 + (tid >> 6) * 16;
  const int arow = rowbase + la;
  const float* ap = hbuf + (size_t)arow * 128 + lb * 8;

  f32x4 acc[8];
#pragma unroll
  for (int ct = 0; ct < 8; ++ct) acc[ct] = (f32x4){0.f, 0.f, 0.f, 0.f};

#pragma unroll
  for (int ks = 0; ks < 4; ++ks) {
    const float4 a0 = *(const float4*)(ap + ks * 32);
    const float4 a1 = *(const float4*)(ap + ks * 32 + 4);
    const float af[8] = {a0.x, a0.y, a0.z, a0.w, a1.x, a1.y, a1.z, a1.w};
    bf16x8 ahi, alo;
#pragma unroll
    for (int j = 0; j < 8; ++j) {
      const unsigned short hh = f2bf(af[j]);
      ahi[j] = (short)hh;
      alo[j] = (short)f2bf(af[j] - bf2f(hh));
    }
#pragma unroll
    for (int ct = 0; ct < 8; ++ct) {
      const int c = ct * 16 + la;
      const bf16x8 b = *(const bf16x8*)(sW + c * LDWU + ks * 16 + lb * 4);
      acc[ct] = __builtin_amdgcn_mfma_f32_16x16x32_bf16(ahi, b, acc[ct], 0, 0, 0);
      acc[ct] = __builtin_amdgcn_mfma_f32_16x16x32_bf16(alo, b, acc[ct], 0, 0, 0);
    }
  }

#pragma unroll
  for (int ct = 0; ct < 8; ++ct) {
    const int col = ct * 16 + la;
    const float bb = b1[col];
    float s = 0.f, q = 0.f;
#pragma unroll
    for (int r = 0; r < 4; ++r) {
      const int row = rowbase + lb * 4 + r;     // C/D: row=(lane>>4)*4+reg
      if (row < NN) {
        const float v = acc[ct][r] + bb;
        const unsigned short hq = f2bf(v);
        h1[(size_t)row * 128 + col] = hq;
        const float vq = bf2f(hq);
        s += vq;
        q += vq * vq;
      }
    }
    s += __shfl_xor(s, 16, 64); q += __shfl_xor(q, 16, 64);
    s += __shfl_xor(s, 32, 64); q += __shfl_xor(q, 32, 64);
    if (lb == 0) { atomicAdd(&ssum[col], s); atomicAdd(&ssq[col], q); }
  }
  __syncthreads();
  if (tid < 128) {
    atomicAdd(&gsum[tid], ssum[tid]);
    atomicAdd(&gsumsq[tid], ssq[tid]);
  }
}

// ---------------------------------------------------------------------------
// K5: out = relu(BN(h1)) @ W2 + b2 via MFMA bf16. A read as bf16; BN affine +
// relu in fp32; requantize to bf16 fragment. h1 pad rows (>= NN) unwritten —
// harmless (A-row only affects its own guarded D-row).
// ---------------------------------------------------------------------------
__global__ __launch_bounds__(256, 4) void k_mfma2(const ushort* __restrict__ h1,
                                                  const ushort* __restrict__ w2t,
                                                  const float* __restrict__ gsum,
                                                  const float* __restrict__ gsq,
                                                  const float* __restrict__ gamma,
                                                  const float* __restrict__ beta,
                                                  const float* __restrict__ b2,
                                                  float* __restrict__ out) {
  __shared__ uint sW[128 * LDWU];
  __shared__ float bnA[128], bnB[128];
  const int tid = threadIdx.x;
  {
    const uint* src = (const uint*)w2t;
    for (int i = tid; i < 8192; i += 256)
      sW[(i >> 6) * LDWU + (i & 63)] = src[i];
  }
  if (tid < 128) {
    const float invN = 1.0f / (float)NN;
    const float m = gsum[tid] * invN;
    const float A = gamma[tid] * rsqrtf(gsq[tid] * invN - m * m + 1e-5f);
    bnA[tid] = A;
    bnB[tid] = beta[tid] - m * A;
  }
  __syncthreads();

  const int l = tid & 63;
  const int la = l & 15;
  const int lb = l >> 4;
  const int rowbase = blockIdx.x * 64 + (tid >> 6) * 16;
  const int arow = rowbase + la;
  const ushort* ap = h1 + (size_t)arow * 128 + lb * 8;

  f32x4 acc[8];
#pragma unroll
  for (int ct = 0; ct < 8; ++ct) acc[ct] = (f32x4){0.f, 0.f, 0.f, 0.f};

#pragma unroll
  for (int ks = 0; ks < 4; ++ks) {
    const int k0 = ks * 32 + lb * 8;
    const bf16x8 araw = *(const bf16x8*)(ap + ks * 32);
    const float4 cA0 = *(const float4*)(bnA + k0);
    const float4 cA1 = *(const float4*)(bnA + k0 + 4);
    const float4 cB0 = *(const float4*)(bnB + k0);
    const float4 cB1 = *(const float4*)(bnB + k0 + 4);
    const float af[8] = {
        fmaxf(fmaf(bf2f((unsigned short)araw[0]), cA0.x, cB0.x), 0.f),
        fmaxf(fmaf(bf2f((unsigned short)araw[1]), cA0.y, cB0.y), 0.f),
        fmaxf(fmaf(bf2f((unsigned short)araw[2]), cA0.z, cB0.z), 0.f),
        fmaxf(fmaf(bf2f((unsigned short)araw[3]), cA0.w, cB0.w), 0.f),
        fmaxf(fmaf(bf2f((unsigned short)araw[4]), cA1.x, cB1.x), 0.f),
        fmaxf(fmaf(bf2f((unsigned short)araw[5]), cA1.y, cB1.y), 0.f),
        fmaxf(fmaf(bf2f((unsigned short)araw[6]), cA1.z, cB1.z), 0.f),
        fmaxf(fmaf(bf2f((unsigned short)araw[7]), cA1.w, cB1.w), 0.f)};
    bf16x8 afr;
#pragma unroll
    for (int j = 0; j < 8; ++j) afr[j] = (short)f2bf(af[j]);
#pragma unroll
    for (int ct = 0; ct < 8; ++ct) {
      const int c = ct * 16 + la;
      const bf16x8 b = *(const bf16x8*)(sW + c * LDWU + ks * 16 + lb * 4);
      acc[ct] = __builtin_amdgcn_mfma_f32_16x16x32_bf16(afr, b, acc[ct], 0, 0, 0);
    }
  }

#pragma unroll
  for (int ct = 0; ct < 8; ++ct) {
    const int col = ct * 16 + la;
    const float bb = b2[col];
#pragma unroll
    for (int r = 0; r < 4; ++r) {
      const int row = rowbase + lb * 4 + r;
      if (row < NN) out[(size_t)row * 128 + col] = acc[ct][r] + bb;
    }
  }
}

extern "C" void kernel_launch(void* const* d_in, const int* in_sizes, int n_in,
                              void* d_out, int out_size, void* d_ws, size_t ws_size,
                              hipStream_t stream) {
  const float* x    = (const float*)d_in[0];
  const int* ea     = (const int*)d_in[1];
  const int* src    = (const int*)d_in[2];
  const int* dst    = (const int*)d_in[3];
  const float* bemb = (const float*)d_in[4];
  const float* epsp = (const float*)d_in[5];
  const float* W1   = (const float*)d_in[6];
  const float* b1   = (const float*)d_in[7];
  const float* gam  = (const float*)d_in[8];
  const float* bet  = (const float*)d_in[9];
  const float* W2   = (const float*)d_in[10];
  const float* b2   = (const float*)d_in[11];
  float* out = (float*)d_out;

  float* ws         = (float*)d_ws;
  float* hbuf       = ws;                                   // NROW*D fp32 (48 pad rows)
  int* bucketCnt    = (int*)(ws + (size_t)NROW * D);        // NB
  float* gsum       = ws + (size_t)NROW * D + NB;           // 128
  float* gsumsq     = gsum + D;                             // 128
  int* beg          = (int*)(gsumsq + D);                   // NN
  int* endp         = beg + NN;                             // NN
  ushort* cth       = (ushort*)(endp + NN);                 // 125*128 bf16 (32 KB)
  ushort* w1t       = cth + 125 * D;                        // 128*128 bf16
  ushort* w2t       = w1t + 16384;                          // 128*128 bf16
  ushort* xh        = w2t + 16384;                          // NN*D bf16
  unsigned* staging = (unsigned*)(xh + (size_t)NN * D);     // NB*CAP (8.0 MB)
  ushort* h1h       = (ushort*)(staging + (size_t)NB * CAP); // NROW*D bf16 (12.8 MB)

  // single memset: contiguous region = hbuf pad rows (6144 f) + bucketCnt
  // (784 i) + gsum/gsumsq (256 f) = 7184 words
  hipMemsetAsync(hbuf + (size_t)NN * D, 0,
                 (size_t)((NROW - NN) * D + NB + 2 * D) * sizeof(float), stream);

  k_bin<<<(NE / EPT + 1023) / 1024, 1024, 0, stream>>>(
      x, bemb, W1, W2, dst, src, ea, bucketCnt, staging, xh, cth, w1t, w2t);
  k_fine<<<NB, 1024, 0, stream>>>(bucketCnt, staging, beg, endp);
  k_agg<<<NN / 8, 256, 0, stream>>>(x, xh, cth, epsp, beg, endp, staging, hbuf);
  k_mfma1<<<NROW / 64, 256, 0, stream>>>(hbuf, w1t, b1, h1h, gsum, gsumsq);
  k_mfma2<<<NROW / 64, 256, 0, stream>>>(h1h, w2t, gsum, gsumsq, gam, bet, b2, out);
}